// Round 7
// baseline (266.928 us; speedup 1.0000x reference)
//
#include <hip/hip_runtime.h>
#include <stdint.h>

#define M_ROWS 8192
#define N_COLS 16384
#define D_DIM  512
#define NNZ_N  65536
#define CHUNKS 8                 // N-chunks of 2048 cols
#define BM 256
#define BN 256
#define BK 32
#define NTC 8                    // N-tiles per chunk (2048/256)
#define NK 16                    // K-steps per nt (512/32)
#define NG (NTC*NK)              // 128 K-steps per block
#define PARTS 32                 // per-row partials: chunk*4 + wc
#define EPSF 1e-20f
#define CFIX 100.0f              // fixed logsumexp offset (natural-log units)
#define C2FIX 144.269504f        // CFIX * log2(e)
#define LOG2E 1.44269504f
#define LN2F  0.6931471806f
#define BUF_ELEMS 16384          // per LDS buffer: A 256x32 + B 256x32 bf16 (32 KB)
#define B_OFF 8192

typedef __attribute__((ext_vector_type(4))) float  f32x4;
typedef __attribute__((ext_vector_type(8))) __bf16 bf16x8;
typedef __attribute__((ext_vector_type(8))) uint16_t u16x8;

// ---------------- fp32 -> bf16 (RNE) ----------------
__device__ __forceinline__ uint16_t f32_to_bf16(float f) {
    uint32_t u = __float_as_uint(f);
    return (uint16_t)((u + 0x7FFFu + ((u >> 16) & 1u)) >> 16);
}
__device__ __forceinline__ float bf2f(uint16_t u) {
    return __uint_as_float(((uint32_t)u) << 16);
}
__device__ __forceinline__ float exp2_fast(float x) {   // v_exp_f32 (2^x)
    float r;
    asm volatile("v_exp_f32 %0, %1" : "=v"(r) : "v"(x));
    return r;
}

// Pb = bf16(P); Qb = bf16(Q * log2e)  (folds base-2 scale into GEMM)
__global__ void convert_all(const float* __restrict__ P, const float* __restrict__ Q,
                            uint16_t* __restrict__ Pb, uint16_t* __restrict__ Qb) {
    const int NP4 = M_ROWS * D_DIM / 4;
    const int NQ4 = N_COLS * D_DIM / 4;
    int stride = gridDim.x * blockDim.x;
    for (int idx = blockIdx.x * blockDim.x + threadIdx.x; idx < NP4 + NQ4; idx += stride) {
        if (idx < NP4) {
            float4 v = ((const float4*)P)[idx];
            ushort4 o;
            o.x = f32_to_bf16(v.x); o.y = f32_to_bf16(v.y);
            o.z = f32_to_bf16(v.z); o.w = f32_to_bf16(v.w);
            ((ushort4*)Pb)[idx] = o;
        } else {
            float4 v = ((const float4*)Q)[idx - NP4];
            ushort4 o;
            o.x = f32_to_bf16(v.x * LOG2E); o.y = f32_to_bf16(v.y * LOG2E);
            o.z = f32_to_bf16(v.z * LOG2E); o.w = f32_to_bf16(v.w * LOG2E);
            ((ushort4*)Qb)[idx - NP4] = o;
        }
    }
}

// ---------------- pos_sum: bf16 gather, block-reduced, 1 atomic/block ----------------
__global__ void pos_kernel(const uint16_t* __restrict__ Pb, const uint16_t* __restrict__ Qb,
                           const int* __restrict__ rows, const int* __restrict__ cols,
                           float* __restrict__ acc) {
    const int NWAVES = 2048;                                    // 512 blocks x 4 waves
    int lane = threadIdx.x & 63;
    int wv = threadIdx.x >> 6;
    int gwave = (blockIdx.x * blockDim.x + threadIdx.x) >> 6;
    float part = 0.f;
    for (int idx = gwave; idx < NNZ_N; idx += NWAVES) {
        int r = rows[idx], c = cols[idx];
        u16x8 p = *(const u16x8*)(Pb + (size_t)r * D_DIM + lane * 8);
        u16x8 q = *(const u16x8*)(Qb + (size_t)c * D_DIM + lane * 8);
        float d = 0.f;
        #pragma unroll
        for (int e = 0; e < 8; ++e) d += bf2f(p[e]) * bf2f(q[e]);
        part += d;
    }
    #pragma unroll
    for (int m = 32; m; m >>= 1) part += __shfl_xor(part, m);
    __shared__ float wsum[4];
    if (lane == 0) wsum[wv] = part;
    __syncthreads();
    if (threadIdx.x == 0)
        atomicAdd(acc, (wsum[0] + wsum[1] + wsum[2] + wsum[3]) * LN2F);
}

// ---------------- async global->LDS, 16B/lane ----------------
__device__ __forceinline__ void gload_lds16(const void* g, void* l) {
    __builtin_amdgcn_global_load_lds((const __attribute__((address_space(1))) unsigned int*)g,
                                     (__attribute__((address_space(3))) unsigned int*)l,
                                     16, 0, 0);
}

// stage halves of K-step g; LDS slot sl of row r holds global k-slot (sl ^ ((r>>1)&3))
__device__ __forceinline__ void stage_A(const uint16_t* __restrict__ Pb,
                                        uint16_t* __restrict__ lds,
                                        int brow, int g, int tid) {
    const int kt = (g & 15) * BK;
    uint16_t* base = lds + (size_t)(g & 3) * BUF_ELEMS;
    const int wu = tid & ~63;
    #pragma unroll
    for (int i = 0; i < 2; ++i) {              // A: 1024 x 16B slots
        int lin = i * 512 + tid;
        int row = lin >> 2, sl = lin & 3;
        int sg = sl ^ ((row >> 1) & 3);
        gload_lds16(Pb + (size_t)(brow + row) * D_DIM + kt + sg * 8,
                    base + (size_t)(i * 512 + wu) * 8);
    }
}
__device__ __forceinline__ void stage_B(const uint16_t* __restrict__ Qb,
                                        uint16_t* __restrict__ lds,
                                        int col0, int g, int tid) {
    const int nt = g >> 4;
    const int kt = (g & 15) * BK;
    uint16_t* base = lds + (size_t)(g & 3) * BUF_ELEMS;
    const int wu = tid & ~63;
    const int qrow0 = col0 + nt * BN;
    #pragma unroll
    for (int i = 0; i < 2; ++i) {              // B: 1024 x 16B slots
        int lin = i * 512 + tid;
        int row = lin >> 2, sl = lin & 3;
        int sg = sl ^ ((row >> 1) & 3);
        gload_lds16(Qb + (size_t)(qrow0 + row) * D_DIM + kt + sg * 8,
                    base + B_OFF + (size_t)(i * 512 + wu) * 8);
    }
}

// ---------------- flash GEMM: quad-buffered, depth-3, m201-style 2 phases/K-step ----------------
// grid 256 blocks (XCD-swizzled: chunk = o&7, rowblock = o>>3), 512 threads = 8 waves (2M x 4N)
__launch_bounds__(512, 2)
__global__ void flash_gemm(const uint16_t* __restrict__ Pb, const uint16_t* __restrict__ Qb,
                           const float* __restrict__ Bw, float* __restrict__ partials) {
    __shared__ __align__(16) uint16_t lds[4 * BUF_ELEMS];   // 128 KB

    const int tid  = threadIdx.x;
    const int lane = tid & 63;
    const int wid  = tid >> 6;
    const int wr   = wid >> 2;            // 0..1
    const int wc   = wid & 3;             // 0..3
    const int fr   = lane & 15;
    const int hi   = lane >> 4;           // 0..3
    // XCD-aware swizzle: 8 XCDs; all 32 row-blocks of one chunk land on one XCD,
    // so that chunk's B-panel (2 MB) stays resident in that XCD's L2.
    const int o     = blockIdx.x;
    const int chunk = o & 7;
    const int brow  = (o >> 3) * BM;
    const int col0  = chunk * (N_COLS / CHUNKS);

    const int kslot = hi ^ ((fr >> 1) & 3);                    // swizzled 16B slot
    const int aoff = (wr * 128 + fr) * BK + kslot * 8;         // + m*512
    const int boff = B_OFF + (wc * 64 + fr) * BK + kslot * 8;  // + n*512

    float s_run[32];
    #pragma unroll
    for (int s = 0; s < 32; ++s) s_run[s] = 0.f;

    // prologue: stage tiles 0,1,2; ensure tile 0 resident for all waves
    stage_A(Pb, lds, brow, 0, tid); stage_B(Qb, lds, col0, 0, tid);
    stage_A(Pb, lds, brow, 1, tid); stage_B(Qb, lds, col0, 1, tid);
    stage_A(Pb, lds, brow, 2, tid); stage_B(Qb, lds, col0, 2, tid);
    asm volatile("s_waitcnt vmcnt(8)" ::: "memory");
    __builtin_amdgcn_s_barrier();

    int g = 0;
    for (int nt = 0; nt < NTC; ++nt) {
        f32x4 acc[8][4];
        #pragma unroll
        for (int m = 0; m < 8; ++m)
            #pragma unroll
            for (int n = 0; n < 4; ++n)
                acc[m][n] = (f32x4){0.f, 0.f, 0.f, 0.f};

        #pragma unroll 1
        for (int t = 0; t < NK; ++t, ++g) {
            const uint16_t* base = lds + (size_t)(g & 3) * BUF_ELEMS;

            // ---- phase 1: {reads B0-3,A0-3 || stage A(g+3)} barrier lgkm(0) 16xMFMA barrier ----
            bf16x8 fb0 = *(const bf16x8*)(base + boff + 0 * 512);
            bf16x8 fb1 = *(const bf16x8*)(base + boff + 1 * 512);
            bf16x8 fb2 = *(const bf16x8*)(base + boff + 2 * 512);
            bf16x8 fb3 = *(const bf16x8*)(base + boff + 3 * 512);
            bf16x8 fa0 = *(const bf16x8*)(base + aoff + 0 * 512);
            bf16x8 fa1 = *(const bf16x8*)(base + aoff + 1 * 512);
            bf16x8 fa2 = *(const bf16x8*)(base + aoff + 2 * 512);
            bf16x8 fa3 = *(const bf16x8*)(base + aoff + 3 * 512);
            if (g + 3 < NG) stage_A(Pb, lds, brow, g + 3, tid);
            __builtin_amdgcn_s_barrier();
            asm volatile("s_waitcnt lgkmcnt(0)" ::: "memory");
            __builtin_amdgcn_sched_barrier(0);
            __builtin_amdgcn_s_setprio(1);
            acc[0][0] = __builtin_amdgcn_mfma_f32_16x16x32_bf16(fa0, fb0, acc[0][0], 0, 0, 0);
            acc[0][1] = __builtin_amdgcn_mfma_f32_16x16x32_bf16(fa0, fb1, acc[0][1], 0, 0, 0);
            acc[0][2] = __builtin_amdgcn_mfma_f32_16x16x32_bf16(fa0, fb2, acc[0][2], 0, 0, 0);
            acc[0][3] = __builtin_amdgcn_mfma_f32_16x16x32_bf16(fa0, fb3, acc[0][3], 0, 0, 0);
            acc[1][0] = __builtin_amdgcn_mfma_f32_16x16x32_bf16(fa1, fb0, acc[1][0], 0, 0, 0);
            acc[1][1] = __builtin_amdgcn_mfma_f32_16x16x32_bf16(fa1, fb1, acc[1][1], 0, 0, 0);
            acc[1][2] = __builtin_amdgcn_mfma_f32_16x16x32_bf16(fa1, fb2, acc[1][2], 0, 0, 0);
            acc[1][3] = __builtin_amdgcn_mfma_f32_16x16x32_bf16(fa1, fb3, acc[1][3], 0, 0, 0);
            acc[2][0] = __builtin_amdgcn_mfma_f32_16x16x32_bf16(fa2, fb0, acc[2][0], 0, 0, 0);
            acc[2][1] = __builtin_amdgcn_mfma_f32_16x16x32_bf16(fa2, fb1, acc[2][1], 0, 0, 0);
            acc[2][2] = __builtin_amdgcn_mfma_f32_16x16x32_bf16(fa2, fb2, acc[2][2], 0, 0, 0);
            acc[2][3] = __builtin_amdgcn_mfma_f32_16x16x32_bf16(fa2, fb3, acc[2][3], 0, 0, 0);
            acc[3][0] = __builtin_amdgcn_mfma_f32_16x16x32_bf16(fa3, fb0, acc[3][0], 0, 0, 0);
            acc[3][1] = __builtin_amdgcn_mfma_f32_16x16x32_bf16(fa3, fb1, acc[3][1], 0, 0, 0);
            acc[3][2] = __builtin_amdgcn_mfma_f32_16x16x32_bf16(fa3, fb2, acc[3][2], 0, 0, 0);
            acc[3][3] = __builtin_amdgcn_mfma_f32_16x16x32_bf16(fa3, fb3, acc[3][3], 0, 0, 0);
            __builtin_amdgcn_s_setprio(0);
            __builtin_amdgcn_s_barrier();            // post-MFMA barrier (m201)

            // ---- phase 2: {reads A4-7 || stage B(g+3)} vmcnt barrier lgkm(0) 16xMFMA barrier ----
            bf16x8 ga0 = *(const bf16x8*)(base + aoff + 4 * 512);
            bf16x8 ga1 = *(const bf16x8*)(base + aoff + 5 * 512);
            bf16x8 ga2 = *(const bf16x8*)(base + aoff + 6 * 512);
            bf16x8 ga3 = *(const bf16x8*)(base + aoff + 7 * 512);
            if (g + 3 < NG) stage_B(Qb, lds, col0, g + 3, tid);
            // guarantee stage(g+1) complete: newer = stage_A/B(g+2) + stage_A/B(g+3)
            if (g + 3 < NG)      asm volatile("s_waitcnt vmcnt(8)" ::: "memory");
            else if (g + 2 < NG) asm volatile("s_waitcnt vmcnt(4)" ::: "memory");
            else                 asm volatile("s_waitcnt vmcnt(0)" ::: "memory");
            __builtin_amdgcn_s_barrier();
            asm volatile("s_waitcnt lgkmcnt(0)" ::: "memory");
            __builtin_amdgcn_sched_barrier(0);
            __builtin_amdgcn_s_setprio(1);
            acc[4][0] = __builtin_amdgcn_mfma_f32_16x16x32_bf16(ga0, fb0, acc[4][0], 0, 0, 0);
            acc[4][1] = __builtin_amdgcn_mfma_f32_16x16x32_bf16(ga0, fb1, acc[4][1], 0, 0, 0);
            acc[4][2] = __builtin_amdgcn_mfma_f32_16x16x32_bf16(ga0, fb2, acc[4][2], 0, 0, 0);
            acc[4][3] = __builtin_amdgcn_mfma_f32_16x16x32_bf16(ga0, fb3, acc[4][3], 0, 0, 0);
            acc[5][0] = __builtin_amdgcn_mfma_f32_16x16x32_bf16(ga1, fb0, acc[5][0], 0, 0, 0);
            acc[5][1] = __builtin_amdgcn_mfma_f32_16x16x32_bf16(ga1, fb1, acc[5][1], 0, 0, 0);
            acc[5][2] = __builtin_amdgcn_mfma_f32_16x16x32_bf16(ga1, fb2, acc[5][2], 0, 0, 0);
            acc[5][3] = __builtin_amdgcn_mfma_f32_16x16x32_bf16(ga1, fb3, acc[5][3], 0, 0, 0);
            acc[6][0] = __builtin_amdgcn_mfma_f32_16x16x32_bf16(ga2, fb0, acc[6][0], 0, 0, 0);
            acc[6][1] = __builtin_amdgcn_mfma_f32_16x16x32_bf16(ga2, fb1, acc[6][1], 0, 0, 0);
            acc[6][2] = __builtin_amdgcn_mfma_f32_16x16x32_bf16(ga2, fb2, acc[6][2], 0, 0, 0);
            acc[6][3] = __builtin_amdgcn_mfma_f32_16x16x32_bf16(ga2, fb3, acc[6][3], 0, 0, 0);
            acc[7][0] = __builtin_amdgcn_mfma_f32_16x16x32_bf16(ga3, fb0, acc[7][0], 0, 0, 0);
            acc[7][1] = __builtin_amdgcn_mfma_f32_16x16x32_bf16(ga3, fb1, acc[7][1], 0, 0, 0);
            acc[7][2] = __builtin_amdgcn_mfma_f32_16x16x32_bf16(ga3, fb2, acc[7][2], 0, 0, 0);
            acc[7][3] = __builtin_amdgcn_mfma_f32_16x16x32_bf16(ga3, fb3, acc[7][3], 0, 0, 0);
            __builtin_amdgcn_s_setprio(0);
            __builtin_amdgcn_s_barrier();            // post-MFMA barrier (m201)
        }

        // epilogue: s += 2^(v2 - C2) * B  (scores already in log2 units via Qb scale)
        const int colbase = col0 + nt * BN + wc * 64;
        float bw0 = Bw[colbase + fr];
        float bw1 = Bw[colbase + 16 + fr];
        float bw2 = Bw[colbase + 32 + fr];
        float bw3 = Bw[colbase + 48 + fr];
        #pragma unroll
        for (int m = 0; m < 8; ++m) {
            #pragma unroll
            for (int j = 0; j < 4; ++j) {
                s_run[m * 4 + j] += exp2_fast(acc[m][0][j] - C2FIX) * bw0
                                  + exp2_fast(acc[m][1][j] - C2FIX) * bw1
                                  + exp2_fast(acc[m][2][j] - C2FIX) * bw2
                                  + exp2_fast(acc[m][3][j] - C2FIX) * bw3;
            }
        }
    }

    // sum across the 16 lanes holding the same rows (different cols)
    #pragma unroll
    for (int s = 0; s < 32; ++s) {
        float sm = s_run[s];
        #pragma unroll
        for (int msk = 1; msk < 16; msk <<= 1) sm += __shfl_xor(sm, msk);
        s_run[s] = sm;
    }
    if (fr == 0) {
        #pragma unroll
        for (int m = 0; m < 8; ++m)
            #pragma unroll
            for (int j = 0; j < 4; ++j) {
                const int row = brow + wr * 128 + m * 16 + hi * 4 + j;
                partials[(size_t)row * PARTS + chunk * 4 + wc] = s_run[m * 4 + j];
            }
    }
}

// ---------------- finalize: sum partials -> wlse -> weighted sum ----------------
__global__ void finalize(const float* __restrict__ partials, const float* __restrict__ A,
                         const float* __restrict__ Ab, float* __restrict__ acc) {
    int i = blockIdx.x * blockDim.x + threadIdx.x;   // 8192 threads
    const float4* p = (const float4*)(partials + (size_t)i * PARTS);
    float s = 0.f;
    #pragma unroll
    for (int k = 0; k < PARTS / 4; ++k) {
        float4 v = p[k];
        s += (v.x + v.y) + (v.z + v.w);
    }
    float wlse = CFIX + __logf(s + EPSF);
    float val = A[i] / Ab[i] * wlse;

    #pragma unroll
    for (int msk = 32; msk; msk >>= 1) val += __shfl_xor(val, msk);
    __shared__ float wsum[4];
    int lane = threadIdx.x & 63, wv = threadIdx.x >> 6;
    if (lane == 0) wsum[wv] = val;
    __syncthreads();
    if (threadIdx.x == 0) atomicAdd(acc + 1, wsum[0] + wsum[1] + wsum[2] + wsum[3]);
}

__global__ void write_out(const float* __restrict__ acc, float* __restrict__ out) {
    out[0] = acc[1] - acc[0];    // loss = sum_wlse - pos_sum (OMEGA=1)
}

extern "C" void kernel_launch(void* const* d_in, const int* in_sizes, int n_in,
                              void* d_out, int out_size, void* d_ws, size_t ws_size,
                              hipStream_t stream) {
    const float* P  = (const float*)d_in[0];
    const float* Q  = (const float*)d_in[1];
    const float* A  = (const float*)d_in[2];
    const float* B  = (const float*)d_in[3];
    const float* Ab = (const float*)d_in[4];
    const int* rows = (const int*)d_in[6];
    const int* cols = (const int*)d_in[7];

    char* ws = (char*)d_ws;
    uint16_t* Pb       = (uint16_t*)ws;                          // 8 MB
    uint16_t* Qb       = (uint16_t*)(ws + 8ull  * 1024 * 1024);  // 16 MB
    float*    partials = (float*)   (ws + 24ull * 1024 * 1024);  // 1 MB (8192*32 floats)
    float*    acc      = (float*)   (ws + 26ull * 1024 * 1024);  // acc[0]=pos, acc[1]=wlse-sum

    hipMemsetAsync(acc, 0, 2 * sizeof(float), stream);
    convert_all<<<2048, 256, 0, stream>>>(P, Q, Pb, Qb);
    flash_gemm<<<256, 512, 0, stream>>>(Pb, Qb, B, partials);
    pos_kernel<<<512, 256, 0, stream>>>(Pb, Qb, rows, cols, acc);
    finalize<<<M_ROWS / 256, 256, 0, stream>>>(partials, A, Ab, acc);
    write_out<<<1, 1, 0, stream>>>(acc, (float*)d_out);
}

// Round 8
// 251.489 us; speedup vs baseline: 1.0614x; 1.0614x over previous
//
#include <hip/hip_runtime.h>
#include <stdint.h>

#define M_ROWS 8192
#define N_COLS 16384
#define D_DIM  512
#define NNZ_N  65536
#define BM 256
#define BN 128                   // column-tile per nt step
#define BK 32
#define CHUNK_COLS 1024          // per-block column span (blockIdx.y)
#define NTC 8                    // column-tiles per block (1024/128)
#define NK 16                    // K-steps per nt (512/32)
#define NG (NTC*NK)              // 128 K-steps per block
#define PARTS 32                 // per-row partials: by*2 + wc
#define EPSF 1e-20f
#define CFIX 100.0f              // fixed logsumexp offset (natural-log units)
#define C2FIX 144.269504f        // CFIX * log2(e)
#define LOG2E 1.44269504f
#define LN2F  0.6931471806f
#define BUF_ELEMS 12288          // per LDS buffer: A 256x32 + B 128x32 bf16 (24 KB)
#define B_OFF 8192

typedef __attribute__((ext_vector_type(4))) float  f32x4;
typedef __attribute__((ext_vector_type(8))) __bf16 bf16x8;
typedef __attribute__((ext_vector_type(8))) uint16_t u16x8;

// ---------------- fp32 -> bf16 (RNE) ----------------
__device__ __forceinline__ uint16_t f32_to_bf16(float f) {
    uint32_t u = __float_as_uint(f);
    return (uint16_t)((u + 0x7FFFu + ((u >> 16) & 1u)) >> 16);
}
__device__ __forceinline__ float bf2f(uint16_t u) {
    return __uint_as_float(((uint32_t)u) << 16);
}
__device__ __forceinline__ float exp2_fast(float x) {   // v_exp_f32 (2^x)
    float r;
    asm volatile("v_exp_f32 %0, %1" : "=v"(r) : "v"(x));
    return r;
}

// Pb = bf16(P); Qb = bf16(Q * log2e)  (folds base-2 scale into GEMM)
__global__ void convert_all(const float* __restrict__ P, const float* __restrict__ Q,
                            uint16_t* __restrict__ Pb, uint16_t* __restrict__ Qb) {
    const int NP4 = M_ROWS * D_DIM / 4;
    const int NQ4 = N_COLS * D_DIM / 4;
    int stride = gridDim.x * blockDim.x;
    for (int idx = blockIdx.x * blockDim.x + threadIdx.x; idx < NP4 + NQ4; idx += stride) {
        if (idx < NP4) {
            float4 v = ((const float4*)P)[idx];
            ushort4 o;
            o.x = f32_to_bf16(v.x); o.y = f32_to_bf16(v.y);
            o.z = f32_to_bf16(v.z); o.w = f32_to_bf16(v.w);
            ((ushort4*)Pb)[idx] = o;
        } else {
            float4 v = ((const float4*)Q)[idx - NP4];
            ushort4 o;
            o.x = f32_to_bf16(v.x * LOG2E); o.y = f32_to_bf16(v.y * LOG2E);
            o.z = f32_to_bf16(v.z * LOG2E); o.w = f32_to_bf16(v.w * LOG2E);
            ((ushort4*)Qb)[idx - NP4] = o;
        }
    }
}

// ---------------- async global->LDS, 16B/lane ----------------
__device__ __forceinline__ void gload_lds16(const void* g, void* l) {
    __builtin_amdgcn_global_load_lds((const __attribute__((address_space(1))) unsigned int*)g,
                                     (__attribute__((address_space(3))) unsigned int*)l,
                                     16, 0, 0);
}

// stage K-step g; LDS slot sl of row r holds global k-slot (sl ^ ((r>>1)&3))
__device__ __forceinline__ void stage_A(const uint16_t* __restrict__ Pb,
                                        uint16_t* __restrict__ lds,
                                        int brow, int g, int tid) {
    const int kt = (g & 15) * BK;
    uint16_t* base = lds + (size_t)(g % 3) * BUF_ELEMS;
    const int wu = tid & ~63;
    #pragma unroll
    for (int i = 0; i < 4; ++i) {              // A: 1024 x 16B slots, 256 threads
        int lin = i * 256 + tid;
        int row = lin >> 2, sl = lin & 3;
        int sg = sl ^ ((row >> 1) & 3);
        gload_lds16(Pb + (size_t)(brow + row) * D_DIM + kt + sg * 8,
                    base + (size_t)(i * 256 + wu) * 8);
    }
}
__device__ __forceinline__ void stage_B(const uint16_t* __restrict__ Qb,
                                        uint16_t* __restrict__ lds,
                                        int col0, int g, int tid) {
    const int nt = g >> 4;
    const int kt = (g & 15) * BK;
    uint16_t* base = lds + (size_t)(g % 3) * BUF_ELEMS;
    const int wu = tid & ~63;
    const int qrow0 = col0 + nt * BN;
    #pragma unroll
    for (int i = 0; i < 2; ++i) {              // B: 512 x 16B slots, 256 threads
        int lin = i * 256 + tid;
        int row = lin >> 2, sl = lin & 3;
        int sg = sl ^ ((row >> 1) & 3);
        gload_lds16(Qb + (size_t)(qrow0 + row) * D_DIM + kt + sg * 8,
                    base + B_OFF + (size_t)(i * 256 + wu) * 8);
    }
}

// ---------------- flash GEMM: 2 blocks/CU, triple-buffered depth-3, 2 phases/K-step ----------------
// grid (32 row-blocks, 16 col-chunks), 256 threads = 4 waves (2M x 2N), per-wave out 128x64.
// pos_sum folded in as a 128-pair tail per block.
__launch_bounds__(256, 2)
__global__ void flash_gemm(const uint16_t* __restrict__ Pb, const uint16_t* __restrict__ Qb,
                           const float* __restrict__ Bw, float* __restrict__ partials,
                           const int* __restrict__ rows, const int* __restrict__ cols,
                           float* __restrict__ acc_out) {
    __shared__ __align__(16) uint16_t lds[3 * BUF_ELEMS];   // 72 KB -> 2 blocks/CU
    __shared__ float wsum[4];

    const int tid  = threadIdx.x;
    const int lane = tid & 63;
    const int wid  = tid >> 6;
    const int wr   = wid >> 1;            // 0..1
    const int wc   = wid & 1;             // 0..1
    const int fr   = lane & 15;
    const int hi   = lane >> 4;           // 0..3
    const int brow = blockIdx.x * BM;
    const int by   = blockIdx.y;          // 0..15
    const int col0 = by * CHUNK_COLS;

    const int kslot = hi ^ ((fr >> 1) & 3);                    // swizzled 16B slot
    const int aoff = (wr * 128 + fr) * BK + kslot * 8;         // + m*512
    const int boff = B_OFF + (wc * 64 + fr) * BK + kslot * 8;  // + n*512

    float s_run[32];
    #pragma unroll
    for (int s = 0; s < 32; ++s) s_run[s] = 0.f;

    // prologue: stage tiles 0,1,2 (6 loads/thread each); ensure tile 0 resident
    stage_A(Pb, lds, brow, 0, tid); stage_B(Qb, lds, col0, 0, tid);
    stage_A(Pb, lds, brow, 1, tid); stage_B(Qb, lds, col0, 1, tid);
    stage_A(Pb, lds, brow, 2, tid); stage_B(Qb, lds, col0, 2, tid);
    asm volatile("s_waitcnt vmcnt(12)" ::: "memory");
    __builtin_amdgcn_s_barrier();

    int g = 0;
    for (int nt = 0; nt < NTC; ++nt) {
        f32x4 acc[8][4];
        #pragma unroll
        for (int m = 0; m < 8; ++m)
            #pragma unroll
            for (int n = 0; n < 4; ++n)
                acc[m][n] = (f32x4){0.f, 0.f, 0.f, 0.f};

        #pragma unroll 1
        for (int t = 0; t < NK; ++t, ++g) {
            const uint16_t* base = lds + (size_t)(g % 3) * BUF_ELEMS;

            // ---- phase 1: {reads B0-3,A0-3 || stage A(g+3)} barrier lgkm(0) 16xMFMA ----
            bf16x8 fb0 = *(const bf16x8*)(base + boff + 0 * 512);
            bf16x8 fb1 = *(const bf16x8*)(base + boff + 1 * 512);
            bf16x8 fb2 = *(const bf16x8*)(base + boff + 2 * 512);
            bf16x8 fb3 = *(const bf16x8*)(base + boff + 3 * 512);
            bf16x8 fa0 = *(const bf16x8*)(base + aoff + 0 * 512);
            bf16x8 fa1 = *(const bf16x8*)(base + aoff + 1 * 512);
            bf16x8 fa2 = *(const bf16x8*)(base + aoff + 2 * 512);
            bf16x8 fa3 = *(const bf16x8*)(base + aoff + 3 * 512);
            if (g + 3 < NG) stage_A(Pb, lds, brow, g + 3, tid);
            __builtin_amdgcn_s_barrier();
            asm volatile("s_waitcnt lgkmcnt(0)" ::: "memory");
            __builtin_amdgcn_sched_barrier(0);
            __builtin_amdgcn_s_setprio(1);
            acc[0][0] = __builtin_amdgcn_mfma_f32_16x16x32_bf16(fa0, fb0, acc[0][0], 0, 0, 0);
            acc[0][1] = __builtin_amdgcn_mfma_f32_16x16x32_bf16(fa0, fb1, acc[0][1], 0, 0, 0);
            acc[0][2] = __builtin_amdgcn_mfma_f32_16x16x32_bf16(fa0, fb2, acc[0][2], 0, 0, 0);
            acc[0][3] = __builtin_amdgcn_mfma_f32_16x16x32_bf16(fa0, fb3, acc[0][3], 0, 0, 0);
            acc[1][0] = __builtin_amdgcn_mfma_f32_16x16x32_bf16(fa1, fb0, acc[1][0], 0, 0, 0);
            acc[1][1] = __builtin_amdgcn_mfma_f32_16x16x32_bf16(fa1, fb1, acc[1][1], 0, 0, 0);
            acc[1][2] = __builtin_amdgcn_mfma_f32_16x16x32_bf16(fa1, fb2, acc[1][2], 0, 0, 0);
            acc[1][3] = __builtin_amdgcn_mfma_f32_16x16x32_bf16(fa1, fb3, acc[1][3], 0, 0, 0);
            acc[2][0] = __builtin_amdgcn_mfma_f32_16x16x32_bf16(fa2, fb0, acc[2][0], 0, 0, 0);
            acc[2][1] = __builtin_amdgcn_mfma_f32_16x16x32_bf16(fa2, fb1, acc[2][1], 0, 0, 0);
            acc[2][2] = __builtin_amdgcn_mfma_f32_16x16x32_bf16(fa2, fb2, acc[2][2], 0, 0, 0);
            acc[2][3] = __builtin_amdgcn_mfma_f32_16x16x32_bf16(fa2, fb3, acc[2][3], 0, 0, 0);
            acc[3][0] = __builtin_amdgcn_mfma_f32_16x16x32_bf16(fa3, fb0, acc[3][0], 0, 0, 0);
            acc[3][1] = __builtin_amdgcn_mfma_f32_16x16x32_bf16(fa3, fb1, acc[3][1], 0, 0, 0);
            acc[3][2] = __builtin_amdgcn_mfma_f32_16x16x32_bf16(fa3, fb2, acc[3][2], 0, 0, 0);
            acc[3][3] = __builtin_amdgcn_mfma_f32_16x16x32_bf16(fa3, fb3, acc[3][3], 0, 0, 0);
            __builtin_amdgcn_s_setprio(0);

            // ---- phase 2: {reads A4-7 || stage B(g+3)} vmcnt barrier lgkm(0) 16xMFMA ----
            bf16x8 ga0 = *(const bf16x8*)(base + aoff + 4 * 512);
            bf16x8 ga1 = *(const bf16x8*)(base + aoff + 5 * 512);
            bf16x8 ga2 = *(const bf16x8*)(base + aoff + 6 * 512);
            bf16x8 ga3 = *(const bf16x8*)(base + aoff + 7 * 512);
            if (g + 3 < NG) stage_B(Qb, lds, col0, g + 3, tid);
            // stage(g+1) must be complete; newer = A+B(g+2)=6, A+B(g+3)=6
            if (g + 3 < NG)      asm volatile("s_waitcnt vmcnt(12)" ::: "memory");
            else if (g + 2 < NG) asm volatile("s_waitcnt vmcnt(6)" ::: "memory");
            else                 asm volatile("s_waitcnt vmcnt(0)" ::: "memory");
            __builtin_amdgcn_s_barrier();
            asm volatile("s_waitcnt lgkmcnt(0)" ::: "memory");
            __builtin_amdgcn_sched_barrier(0);
            __builtin_amdgcn_s_setprio(1);
            acc[4][0] = __builtin_amdgcn_mfma_f32_16x16x32_bf16(ga0, fb0, acc[4][0], 0, 0, 0);
            acc[4][1] = __builtin_amdgcn_mfma_f32_16x16x32_bf16(ga0, fb1, acc[4][1], 0, 0, 0);
            acc[4][2] = __builtin_amdgcn_mfma_f32_16x16x32_bf16(ga0, fb2, acc[4][2], 0, 0, 0);
            acc[4][3] = __builtin_amdgcn_mfma_f32_16x16x32_bf16(ga0, fb3, acc[4][3], 0, 0, 0);
            acc[5][0] = __builtin_amdgcn_mfma_f32_16x16x32_bf16(ga1, fb0, acc[5][0], 0, 0, 0);
            acc[5][1] = __builtin_amdgcn_mfma_f32_16x16x32_bf16(ga1, fb1, acc[5][1], 0, 0, 0);
            acc[5][2] = __builtin_amdgcn_mfma_f32_16x16x32_bf16(ga1, fb2, acc[5][2], 0, 0, 0);
            acc[5][3] = __builtin_amdgcn_mfma_f32_16x16x32_bf16(ga1, fb3, acc[5][3], 0, 0, 0);
            acc[6][0] = __builtin_amdgcn_mfma_f32_16x16x32_bf16(ga2, fb0, acc[6][0], 0, 0, 0);
            acc[6][1] = __builtin_amdgcn_mfma_f32_16x16x32_bf16(ga2, fb1, acc[6][1], 0, 0, 0);
            acc[6][2] = __builtin_amdgcn_mfma_f32_16x16x32_bf16(ga2, fb2, acc[6][2], 0, 0, 0);
            acc[6][3] = __builtin_amdgcn_mfma_f32_16x16x32_bf16(ga2, fb3, acc[6][3], 0, 0, 0);
            acc[7][0] = __builtin_amdgcn_mfma_f32_16x16x32_bf16(ga3, fb0, acc[7][0], 0, 0, 0);
            acc[7][1] = __builtin_amdgcn_mfma_f32_16x16x32_bf16(ga3, fb1, acc[7][1], 0, 0, 0);
            acc[7][2] = __builtin_amdgcn_mfma_f32_16x16x32_bf16(ga3, fb2, acc[7][2], 0, 0, 0);
            acc[7][3] = __builtin_amdgcn_mfma_f32_16x16x32_bf16(ga3, fb3, acc[7][3], 0, 0, 0);
            __builtin_amdgcn_s_setprio(0);
        }

        // epilogue: s += 2^(v2 - C2) * B  (scores already in log2 units via Qb scale)
        const int colbase = col0 + nt * BN + wc * 64;
        float bw0 = Bw[colbase + fr];
        float bw1 = Bw[colbase + 16 + fr];
        float bw2 = Bw[colbase + 32 + fr];
        float bw3 = Bw[colbase + 48 + fr];
        #pragma unroll
        for (int m = 0; m < 8; ++m) {
            #pragma unroll
            for (int j = 0; j < 4; ++j) {
                s_run[m * 4 + j] += exp2_fast(acc[m][0][j] - C2FIX) * bw0
                                  + exp2_fast(acc[m][1][j] - C2FIX) * bw1
                                  + exp2_fast(acc[m][2][j] - C2FIX) * bw2
                                  + exp2_fast(acc[m][3][j] - C2FIX) * bw3;
            }
        }
    }

    // sum across the 16 lanes holding the same rows (different cols)
    #pragma unroll
    for (int s = 0; s < 32; ++s) {
        float sm = s_run[s];
        #pragma unroll
        for (int msk = 1; msk < 16; msk <<= 1) sm += __shfl_xor(sm, msk);
        s_run[s] = sm;
    }
    if (fr == 0) {
        #pragma unroll
        for (int m = 0; m < 8; ++m)
            #pragma unroll
            for (int j = 0; j < 4; ++j) {
                const int row = brow + wr * 128 + m * 16 + hi * 4 + j;
                partials[(size_t)row * PARTS + by * 2 + wc] = s_run[m * 4 + j];
            }
    }

    // ---- pos_sum tail: this block's 128 coordinate pairs (bf16; x ln2 for Qb scale) ----
    {
        const int bid = blockIdx.y * 32 + blockIdx.x;          // 0..511
        float part = 0.f;
        #pragma unroll 4
        for (int it = 0; it < 32; ++it) {
            int idx = bid * 128 + wid * 32 + it;
            int r = rows[idx], c = cols[idx];
            u16x8 p = *(const u16x8*)(Pb + (size_t)r * D_DIM + lane * 8);
            u16x8 q = *(const u16x8*)(Qb + (size_t)c * D_DIM + lane * 8);
            float d = 0.f;
            #pragma unroll
            for (int e = 0; e < 8; ++e) d += bf2f(p[e]) * bf2f(q[e]);
            part += d;
        }
        #pragma unroll
        for (int m = 32; m; m >>= 1) part += __shfl_xor(part, m);
        if (lane == 0) wsum[wid] = part;
        __syncthreads();
        if (tid == 0)
            atomicAdd(acc_out, (wsum[0] + wsum[1] + wsum[2] + wsum[3]) * LN2F);
    }
}

// ---------------- finalize: sum partials -> wlse -> weighted sum ----------------
__global__ void finalize(const float* __restrict__ partials, const float* __restrict__ A,
                         const float* __restrict__ Ab, float* __restrict__ acc) {
    int i = blockIdx.x * blockDim.x + threadIdx.x;   // 8192 threads
    const float4* p = (const float4*)(partials + (size_t)i * PARTS);
    float s = 0.f;
    #pragma unroll
    for (int k = 0; k < PARTS / 4; ++k) {
        float4 v = p[k];
        s += (v.x + v.y) + (v.z + v.w);
    }
    float wlse = CFIX + __logf(s + EPSF);
    float val = A[i] / Ab[i] * wlse;

    #pragma unroll
    for (int msk = 32; msk; msk >>= 1) val += __shfl_xor(val, msk);
    __shared__ float wsum[4];
    int lane = threadIdx.x & 63, wv = threadIdx.x >> 6;
    if (lane == 0) wsum[wv] = val;
    __syncthreads();
    if (threadIdx.x == 0) atomicAdd(acc + 1, wsum[0] + wsum[1] + wsum[2] + wsum[3]);
}

__global__ void write_out(const float* __restrict__ acc, float* __restrict__ out) {
    out[0] = acc[1] - acc[0];    // loss = sum_wlse - pos_sum (OMEGA=1)
}

extern "C" void kernel_launch(void* const* d_in, const int* in_sizes, int n_in,
                              void* d_out, int out_size, void* d_ws, size_t ws_size,
                              hipStream_t stream) {
    const float* P  = (const float*)d_in[0];
    const float* Q  = (const float*)d_in[1];
    const float* A  = (const float*)d_in[2];
    const float* B  = (const float*)d_in[3];
    const float* Ab = (const float*)d_in[4];
    const int* rows = (const int*)d_in[6];
    const int* cols = (const int*)d_in[7];

    char* ws = (char*)d_ws;
    uint16_t* Pb       = (uint16_t*)ws;                          // 8 MB
    uint16_t* Qb       = (uint16_t*)(ws + 8ull  * 1024 * 1024);  // 16 MB
    float*    partials = (float*)   (ws + 24ull * 1024 * 1024);  // 1 MB (8192*32 floats)
    float*    acc      = (float*)   (ws + 26ull * 1024 * 1024);  // acc[0]=pos, acc[1]=wlse-sum

    hipMemsetAsync(acc, 0, 2 * sizeof(float), stream);
    convert_all<<<2048, 256, 0, stream>>>(P, Q, Pb, Qb);
    flash_gemm<<<dim3(32, 16), 256, 0, stream>>>(Pb, Qb, B, partials, rows, cols, acc);
    finalize<<<M_ROWS / 256, 256, 0, stream>>>(partials, A, Ab, acc);
    write_out<<<1, 1, 0, stream>>>(acc, (float*)d_out);
}